// Round 7
// baseline (49.504 us; speedup 1.0000x reference)
//
#include <hip/hip_runtime.h>

// NoiseLearnModule: out = x + where(0<=bin<16, eps * sigmoid(params[f,bin]) * 0.1, 0)
// bin = searchsorted(bins[f], x, side='right') - 1
// x,eps [65536,256] f32; bins [256,17] f32; params [256*16] f32.
//
// R7 = R6 structure (U=2, named scalars, float4 I/O, [e][f] bins scan) with
// the scale gather reverted to f32 and laid out [16][257]:
//   gather dword = jc*257 + 4t + c  ->  bank = (jc + 4t + c) % 32
// so the data-dependent bin index SPREADS banks (~2-3-way) instead of the
// unpadded layout's jc-invisible 8-way. LDS pipe: (17 b128 + 8 gathers) per
// 512 elems = ~0.52 cy/elem = ~14 us/CU < ~21 us HBM floor -> memory-bound.

#define NFEAT 256
#define NBINS 16
#define NEDGE 17
#define SPAD  257              // f32 scale row stride: jc*257 spreads banks
#define NOISE_SCALE 0.1f

__global__ __launch_bounds__(256) void noise_learn_kernel(
    const float* __restrict__ x,
    const float* __restrict__ bins,
    const float* __restrict__ eps,
    const float* __restrict__ params,
    float* __restrict__ out,
    int total4)
{
    __shared__ float s_bins[NEDGE * NFEAT];     // 17408 B, [e][f]
    __shared__ float s_scale[NBINS * SPAD];     // 16448 B, [k][f] padded

    const int t = threadIdx.x;

    // Stage bins transposed: coalesced read bins[f*17+e], write [e][f].
    #pragma unroll
    for (int i = t; i < NEDGE * NFEAT; i += 256) {     // 17 exact iters
        const float v = bins[i];
        const int f = i / NEDGE;
        const int e = i - f * NEDGE;
        s_bins[e * NFEAT + f] = v;
    }

    // Stage sigmoid(params) transposed: [k][SPAD].
    #pragma unroll
    for (int i = t; i < NFEAT * NBINS; i += 256) {     // 16 exact iters
        const float p = params[i];
        const int f = i >> 4;
        const int k = i & (NBINS - 1);
        s_scale[k * SPAD + f] = 1.0f / (1.0f + __expf(-p));
    }
    __syncthreads();

    const int nthreads = gridDim.x * 256;              // multiple of 64
    const int gid = blockIdx.x * 256 + t;
    const int fbase = (t & 63) * 4;                    // loop-invariant features

    // total4 % (2*nthreads) == 0 here (4194304 = 4 * 1048576), no tail.
    for (int base = gid; base + nthreads < total4; base += 2 * nthreads) {
        const int g0 = base;
        const int g1 = base + nthreads;

        const float4 xa = reinterpret_cast<const float4*>(x)[g0];
        const float4 xb = reinterpret_cast<const float4*>(x)[g1];
        const float4 ea = reinterpret_cast<const float4*>(eps)[g0];
        const float4 eb = reinterpret_cast<const float4*>(eps)[g1];

        int a0 = 0, a1 = 0, a2 = 0, a3 = 0;
        int b0 = 0, b1 = 0, b2 = 0, b3 = 0;

        #pragma unroll
        for (int e = 0; e < NEDGE; ++e) {              // one edge pass serves 8 elems
            const float4 be = *reinterpret_cast<const float4*>(&s_bins[e * NFEAT + fbase]);
            a0 += (be.x <= xa.x) ? 1 : 0;
            a1 += (be.y <= xa.y) ? 1 : 0;
            a2 += (be.z <= xa.z) ? 1 : 0;
            a3 += (be.w <= xa.w) ? 1 : 0;
            b0 += (be.x <= xb.x) ? 1 : 0;
            b1 += (be.y <= xb.y) ? 1 : 0;
            b2 += (be.z <= xb.z) ? 1 : 0;
            b3 += (be.w <= xb.w) ? 1 : 0;
        }

        float4 oa, ob;
        {
            const int idx = a0 - 1;
            const int jc = idx < 0 ? 0 : (idx > NBINS - 1 ? NBINS - 1 : idx);
            const float sc = s_scale[jc * SPAD + fbase + 0];
            oa.x = xa.x + (((unsigned)idx < (unsigned)NBINS) ? ea.x * sc * NOISE_SCALE : 0.0f);
        }
        {
            const int idx = a1 - 1;
            const int jc = idx < 0 ? 0 : (idx > NBINS - 1 ? NBINS - 1 : idx);
            const float sc = s_scale[jc * SPAD + fbase + 1];
            oa.y = xa.y + (((unsigned)idx < (unsigned)NBINS) ? ea.y * sc * NOISE_SCALE : 0.0f);
        }
        {
            const int idx = a2 - 1;
            const int jc = idx < 0 ? 0 : (idx > NBINS - 1 ? NBINS - 1 : idx);
            const float sc = s_scale[jc * SPAD + fbase + 2];
            oa.z = xa.z + (((unsigned)idx < (unsigned)NBINS) ? ea.z * sc * NOISE_SCALE : 0.0f);
        }
        {
            const int idx = a3 - 1;
            const int jc = idx < 0 ? 0 : (idx > NBINS - 1 ? NBINS - 1 : idx);
            const float sc = s_scale[jc * SPAD + fbase + 3];
            oa.w = xa.w + (((unsigned)idx < (unsigned)NBINS) ? ea.w * sc * NOISE_SCALE : 0.0f);
        }
        {
            const int idx = b0 - 1;
            const int jc = idx < 0 ? 0 : (idx > NBINS - 1 ? NBINS - 1 : idx);
            const float sc = s_scale[jc * SPAD + fbase + 0];
            ob.x = xb.x + (((unsigned)idx < (unsigned)NBINS) ? eb.x * sc * NOISE_SCALE : 0.0f);
        }
        {
            const int idx = b1 - 1;
            const int jc = idx < 0 ? 0 : (idx > NBINS - 1 ? NBINS - 1 : idx);
            const float sc = s_scale[jc * SPAD + fbase + 1];
            ob.y = xb.y + (((unsigned)idx < (unsigned)NBINS) ? eb.y * sc * NOISE_SCALE : 0.0f);
        }
        {
            const int idx = b2 - 1;
            const int jc = idx < 0 ? 0 : (idx > NBINS - 1 ? NBINS - 1 : idx);
            const float sc = s_scale[jc * SPAD + fbase + 2];
            ob.z = xb.z + (((unsigned)idx < (unsigned)NBINS) ? eb.z * sc * NOISE_SCALE : 0.0f);
        }
        {
            const int idx = b3 - 1;
            const int jc = idx < 0 ? 0 : (idx > NBINS - 1 ? NBINS - 1 : idx);
            const float sc = s_scale[jc * SPAD + fbase + 3];
            ob.w = xb.w + (((unsigned)idx < (unsigned)NBINS) ? eb.w * sc * NOISE_SCALE : 0.0f);
        }

        reinterpret_cast<float4*>(out)[g0] = oa;
        reinterpret_cast<float4*>(out)[g1] = ob;
    }
}

extern "C" void kernel_launch(void* const* d_in, const int* in_sizes, int n_in,
                              void* d_out, int out_size, void* d_ws, size_t ws_size,
                              hipStream_t stream) {
    const float* x      = (const float*)d_in[0];
    const float* bins   = (const float*)d_in[1];
    const float* eps    = (const float*)d_in[2];
    const float* params = (const float*)d_in[3];
    float* out = (float*)d_out;

    const int total4 = out_size / 4;   // 4,194,304 = 2048*256*2*4 -> exactly 4 iters
    dim3 block(256);
    dim3 grid(2048);
    noise_learn_kernel<<<grid, block, 0, stream>>>(x, bins, eps, params, out, total4);
}

// Round 8
// 39.099 us; speedup vs baseline: 1.2661x; 1.2661x over previous
//
#include <hip/hip_runtime.h>

// NoiseLearnModule: out = x + where(0<=bin<16, eps * sigmoid(params[f,bin]) * 0.1, 0)
// bin = searchsorted(bins[f], x, side='right') - 1
// x,eps [65536,256] f32; bins [256,17] f32; params [256*16] f32.
//
// R8: scan moved OUT of LDS (17 edges in registers, 1 feature/thread, proven
// to fit: R4 ran this shape at VGPR=36, zero spill). LDS holds only the
// sigmoid table [k][256]; gather addr = jc*256+t -> bank t%32 -> 2 lanes/bank
// (free), independent of the data-dependent jc. Staging is bank-clean:
// thread t owns feature t (reads params[t*16+k] - scattered but L2-cached
// one-time; writes s[k*256+t] - conflict-free). Main loop: 4-way hand-named
// unroll -> 8 coalesced scalar loads in flight, 4 independent reg-scan chains,
// 4 conflict-free gathers, no barriers, no LDS scan traffic at all.

#define NFEAT 256
#define NBINS 16
#define NEDGE 17
#define NOISE_SCALE 0.1f

__global__ __launch_bounds__(256) void noise_learn_kernel(
    const float* __restrict__ x,
    const float* __restrict__ bins,
    const float* __restrict__ eps,
    const float* __restrict__ params,
    float* __restrict__ out,
    int total)
{
    __shared__ float s_sig[NBINS * NFEAT];   // 16384 B, [k][f], f fast

    const int t = threadIdx.x;               // == feature id

    // Bank-clean staging: thread t computes feature t's 16 sigmoids.
    // Reads are scattered (stride 64B) but the 16 KB table is L2/L1-resident
    // after the first blocks; writes hit bank t%32 -> conflict-free.
    #pragma unroll
    for (int k = 0; k < NBINS; ++k) {
        const float p = params[t * NBINS + k];
        s_sig[k * NFEAT + t] = 1.0f / (1.0f + __expf(-p));
    }

    // This feature's 17 edges -> registers (R4-proven: fits, no spill).
    float ed[NEDGE];
    #pragma unroll
    for (int i = 0; i < NEDGE; ++i)
        ed[i] = bins[t * NEDGE + i];

    __syncthreads();

    const int n = gridDim.x * 256;           // multiple of 256 -> feature invariant
    const int gid = blockIdx.x * 256 + t;

    // total = 16,777,216 = 2048*256 * 4 * 8 -> exactly 8 guard-free iterations.
    for (int base = gid; base + 3 * n < total; base += 4 * n) {
        const int gA = base, gB = base + n, gC = base + 2 * n, gD = base + 3 * n;

        // 8 independent coalesced loads in flight.
        const float xA = x[gA], xB = x[gB], xC = x[gC], xD = x[gD];
        const float pA = eps[gA], pB = eps[gB], pC = eps[gC], pD = eps[gD];

        int cA = 0, cB = 0, cC = 0, cD = 0;  // #edges <= x (side='right')
        #pragma unroll
        for (int i = 0; i < NEDGE; ++i) {
            cA += (ed[i] <= xA) ? 1 : 0;
            cB += (ed[i] <= xB) ? 1 : 0;
            cC += (ed[i] <= xC) ? 1 : 0;
            cD += (ed[i] <= xD) ? 1 : 0;
        }

        {
            const int idx = cA - 1;
            const int jc = idx < 0 ? 0 : (idx > NBINS - 1 ? NBINS - 1 : idx);
            const float sc = s_sig[jc * NFEAT + t];      // bank t%32: free
            out[gA] = xA + (((unsigned)idx < (unsigned)NBINS) ? pA * sc * NOISE_SCALE : 0.0f);
        }
        {
            const int idx = cB - 1;
            const int jc = idx < 0 ? 0 : (idx > NBINS - 1 ? NBINS - 1 : idx);
            const float sc = s_sig[jc * NFEAT + t];
            out[gB] = xB + (((unsigned)idx < (unsigned)NBINS) ? pB * sc * NOISE_SCALE : 0.0f);
        }
        {
            const int idx = cC - 1;
            const int jc = idx < 0 ? 0 : (idx > NBINS - 1 ? NBINS - 1 : idx);
            const float sc = s_sig[jc * NFEAT + t];
            out[gC] = xC + (((unsigned)idx < (unsigned)NBINS) ? pC * sc * NOISE_SCALE : 0.0f);
        }
        {
            const int idx = cD - 1;
            const int jc = idx < 0 ? 0 : (idx > NBINS - 1 ? NBINS - 1 : idx);
            const float sc = s_sig[jc * NFEAT + t];
            out[gD] = xD + (((unsigned)idx < (unsigned)NBINS) ? pD * sc * NOISE_SCALE : 0.0f);
        }
    }
}

extern "C" void kernel_launch(void* const* d_in, const int* in_sizes, int n_in,
                              void* d_out, int out_size, void* d_ws, size_t ws_size,
                              hipStream_t stream) {
    const float* x      = (const float*)d_in[0];
    const float* bins   = (const float*)d_in[1];
    const float* eps    = (const float*)d_in[2];
    const float* params = (const float*)d_in[3];
    float* out = (float*)d_out;

    dim3 block(256);
    dim3 grid(2048);   // 8 blocks/CU resident (16.4 KB LDS); 8 iters of 4-unroll
    noise_learn_kernel<<<grid, block, 0, stream>>>(x, bins, eps, params, out, out_size);
}

// Round 9
// 38.719 us; speedup vs baseline: 1.2785x; 1.0098x over previous
//
#include <hip/hip_runtime.h>

// NoiseLearnModule: out = x + where(0<=bin<16, eps * sigmoid(params[f,bin]) * 0.1, 0)
// bin = searchsorted(bins[f], x, side='right') - 1
// x,eps [65536,256] f32; bins [256,17] f32; params [256*16] f32.
//
// R9: ZERO-LDS design. Thread t owns feature t. Both tables live in regs:
//   ed[17]  = bin edges
//   sg[16]  = 0.1 * sigmoid(params)   (pre-scaled)
// The scan+gather is one fused cndmask chain (compile-time indices only):
//   s = sg[0]; for i=1..15: s = (ed[i] <= x) ? sg[i] : s
// selects sg[clamp(count-1, 0, 15)] exactly; validity = (ed[0]<=x) && (x<ed[16]).
// No count, no clamp, no LDS, no barriers, no lgkmcnt in the main loop.
// U=4 hand-named unroll: 8 coalesced dword loads in flight per iter.

#define NFEAT 256
#define NBINS 16
#define NEDGE 17
#define NOISE_SCALE 0.1f

__global__ __launch_bounds__(256, 4) void noise_learn_kernel(
    const float* __restrict__ x,
    const float* __restrict__ bins,
    const float* __restrict__ eps,
    const float* __restrict__ params,
    float* __restrict__ out,
    int total)
{
    const int t = threadIdx.x;               // == feature id

    // Prologue (one-time, latency hidden by wave count):
    float ed[NEDGE];
    #pragma unroll
    for (int i = 0; i < NEDGE; ++i)
        ed[i] = bins[t * NEDGE + i];

    float sg[NBINS];                         // pre-scaled: 0.1 * sigmoid(p)
    #pragma unroll
    for (int k = 0; k < NBINS; ++k)
        sg[k] = NOISE_SCALE / (1.0f + __expf(-params[t * NBINS + k]));

    const int n = gridDim.x * 256;           // multiple of 256 -> feature invariant
    const int gid = blockIdx.x * 256 + t;

    // total = 16,777,216 = 2048*256*4*8 -> exactly 8 guard-free iterations.
    for (int base = gid; base + 3 * n < total; base += 4 * n) {
        const int gA = base, gB = base + n, gC = base + 2 * n, gD = base + 3 * n;

        const float xA = x[gA], xB = x[gB], xC = x[gC], xD = x[gD];
        const float pA = eps[gA], pB = eps[gB], pC = eps[gC], pD = eps[gD];

        // Fused scan+select: 4 independent cndmask chains.
        float sA = sg[0], sB = sg[0], sC = sg[0], sD = sg[0];
        #pragma unroll
        for (int i = 1; i < NBINS; ++i) {
            sA = (ed[i] <= xA) ? sg[i] : sA;
            sB = (ed[i] <= xB) ? sg[i] : sB;
            sC = (ed[i] <= xC) ? sg[i] : sC;
            sD = (ed[i] <= xD) ? sg[i] : sD;
        }

        const float vA = (ed[0] <= xA && xA < ed[NEDGE - 1]) ? sA : 0.0f;
        const float vB = (ed[0] <= xB && xB < ed[NEDGE - 1]) ? sB : 0.0f;
        const float vC = (ed[0] <= xC && xC < ed[NEDGE - 1]) ? sC : 0.0f;
        const float vD = (ed[0] <= xD && xD < ed[NEDGE - 1]) ? sD : 0.0f;

        out[gA] = fmaf(pA, vA, xA);
        out[gB] = fmaf(pB, vB, xB);
        out[gC] = fmaf(pC, vC, xC);
        out[gD] = fmaf(pD, vD, xD);
    }
}

extern "C" void kernel_launch(void* const* d_in, const int* in_sizes, int n_in,
                              void* d_out, int out_size, void* d_ws, size_t ws_size,
                              hipStream_t stream) {
    const float* x      = (const float*)d_in[0];
    const float* bins   = (const float*)d_in[1];
    const float* eps    = (const float*)d_in[2];
    const float* params = (const float*)d_in[3];
    float* out = (float*)d_out;

    dim3 block(256);
    dim3 grid(2048);   // zero LDS; 8 iters of U=4 per thread, no tail
    noise_learn_kernel<<<grid, block, 0, stream>>>(x, bins, eps, params, out, out_size);
}